// Round 4
// baseline (166.008 us; speedup 1.0000x reference)
//
#include <hip/hip_runtime.h>
#include <hip/hip_cooperative_groups.h>
#include <math.h>

namespace cg = cooperative_groups;

#define N_ATOMS 512
#define MAX_B 128
#define NBUCK 32
#define WIN 0.65f   // 6.5 sigma; exp(-50*0.65^2) ~ 7e-10, negligible vs 0.235 budget

// ---------------- fused cooperative kernel (main path) ----------------
// Grid: F*64 blocks, 256 threads. Block = (frame, 4 bow-tie row-pairs) = 2048 pairs.
// Phase A: bucketed bin-centric partial histogram -> part[bin][block] (transposed).
// grid.sync(); Phase B: block b (< B) reduces bin b's column and writes outputs.
__global__ __launch_bounds__(256) void rdf_fused(
    const float* __restrict__ traj, const float* __restrict__ cell,
    const float* __restrict__ r_list, float* __restrict__ part,
    float* __restrict__ out, int B, int F, int nblocks)
{
    __shared__ float qx[N_ATOMS], qy[N_ATOMS], qz[N_ATOMS];
    __shared__ float dsorted[2048];
    __shared__ int   cnt[NBUCK];
    __shared__ int   start[NBUCK + 1];
    __shared__ int   cursor[NBUCK];
    __shared__ float accbuf[256];

    const int frame = blockIdx.x >> 6;
    const int sub   = blockIdx.x & 63;
    const int tid   = threadIdx.x;

    const float* q = traj + (size_t)frame * (N_ATOMS * 3);
    for (int a = tid; a < N_ATOMS; a += 256) {
        qx[a] = q[3 * a + 0];
        qy[a] = q[3 * a + 1];
        qz[a] = q[3 * a + 2];
    }
    if (tid < NBUCK) cnt[tid] = 0;
    __syncthreads();

    const float L = cell[0];
    const float invL = 1.0f / L;
    const float cutoff_sq = 0.25f * L * L;
    const float inv_bw = (float)NBUCK / (0.5f * L);

    // ---- phase A1: distances + bucket counts (8 pairs per thread) ----
    float dval[8];
    int   dbuck[8];
    #pragma unroll
    for (int s = 0; s < 8; ++s) {
        const int qidx = s * 256 + tid;            // [0, 2048)
        const int rp   = sub * 4 + (qidx >> 9);    // row-pair [0, 256)
        const int qq   = qidx & 511;
        const int lenA = 511 - rp;                 // row rp: j in (rp, 511]
        const bool inA = qq < lenA;
        const int i = inA ? rp : (510 - rp);       // partner row 510-rp
        const int j = inA ? (rp + 1 + qq) : qq;
        const bool vp = !(rp == 255 && !inA);      // self-paired middle row: half only

        float dx = qx[j] - qx[i];
        float dy = qy[j] - qy[i];
        float dz = qz[j] - qz[i];
        dx -= L * floorf(dx * invL + 0.5f);
        dy -= L * floorf(dy * invL + 0.5f);
        dz -= L * floorf(dz * invL + 0.5f);
        const float d2 = dx * dx + dy * dy + dz * dz;

        dbuck[s] = -1;
        dval[s]  = 0.0f;
        if (vp && d2 < cutoff_sq && d2 != 0.0f) {
            const float d = sqrtf(d2);
            int bu = (int)(d * inv_bw);
            if (bu > NBUCK - 1) bu = NBUCK - 1;
            dval[s]  = d;
            dbuck[s] = bu;
            atomicAdd(&cnt[bu], 1);                // native ds_add_u32
        }
    }
    __syncthreads();

    // ---- phase A2: exclusive prefix scan of 32 bucket counts (one wave) ----
    if (tid < NBUCK) {
        const int v = cnt[tid];
        int incl = v;
        #pragma unroll
        for (int off = 1; off < NBUCK; off <<= 1) {
            const int n = __shfl_up(incl, off, 64);
            if (tid >= off) incl += n;
        }
        start[tid + 1] = incl;
        cursor[tid] = incl - v;
        if (tid == 0) start[0] = 0;
    }
    __syncthreads();

    // ---- phase A3: scatter distances into bucket-sorted order ----
    #pragma unroll
    for (int s = 0; s < 8; ++s) {
        if (dbuck[s] >= 0) {
            const int pos = atomicAdd(&cursor[dbuck[s]], 1);
            dsorted[pos] = dval[s];
        }
    }
    __syncthreads();

    // ---- phase A4: bin-centric accumulation over windowed bucket range ----
    const int k = tid & 127;
    const int g = tid >> 7;
    float acc = 0.0f;
    if (k < B) {
        const float rk = r_list[k];
        const float c1 = -50.0f;
        const float c2 = 100.0f * rk;
        const float c3 = -50.0f * rk * rk;
        int blo = (int)(fmaxf((rk - WIN) * inv_bw, 0.0f));
        int bhi = (int)((rk + WIN) * inv_bw);
        if (bhi > NBUCK - 1) bhi = NBUCK - 1;
        const int lo = start[blo];
        const int hi = start[bhi + 1];
        for (int idx = lo + g; idx < hi; idx += 2) {
            const float d = dsorted[idx];
            acc += __expf(fmaf(d, fmaf(c1, d, c2), c3));
        }
    }
    accbuf[tid] = acc;
    __syncthreads();

    // transposed partial write: part[bin][block] (coalescing pushed to wide phase)
    if (tid < MAX_B)
        part[(size_t)tid * nblocks + blockIdx.x] = accbuf[tid] + accbuf[tid + 128];

    cg::this_grid().sync();

    // ---- phase B: block b reduces bin b (coalesced column read) ----
    const int b = blockIdx.x;
    if (b < B) {
        const float* col = part + (size_t)b * nblocks;
        float s = 0.0f;
        for (int t = tid; t < nblocks; t += 256) s += col[t];
        accbuf[tid] = s;
        __syncthreads();
        #pragma unroll
        for (int off = 128; off > 0; off >>= 1) {
            if (tid < off) accbuf[tid] += accbuf[tid + off];
            __syncthreads();
        }
        if (tid == 0) {
            const float r = r_list[b];
            out[b] = r;                                    // output 0: r_list
            const float det = cell[0] * cell[4] * cell[8];
            const float rp = r + 0.05f;
            const float rm = r - 0.05f;
            const float v = (4.0f * (float)M_PI / 3.0f) * (rp * rp * rp - rm * rm * rm);
            const float inv_sqrt2pi = 0.3989422804014327f;
            const float h = accbuf[0] * inv_sqrt2pi / (float)F;
            const float gr = h / v * det / (float)(N_ATOMS - 1) / (float)N_ATOMS * 2.0f;
            out[B + b] = gr;                               // output 1: gr
        }
    }
}

// ---------------- fallback path (small ws): 3 dispatches ----------------
__global__ void zero_kernel(float* p, int n) {
    int t = blockIdx.x * blockDim.x + threadIdx.x;
    if (t < n) p[t] = 0.0f;
}

__global__ __launch_bounds__(256) void pair_kernel_atomic(
    const float* __restrict__ traj, const float* __restrict__ cell,
    const float* __restrict__ r_list, float* __restrict__ hist, int B)
{
    __shared__ float qx[N_ATOMS], qy[N_ATOMS], qz[N_ATOMS];
    __shared__ float dsorted[2048];
    __shared__ int   cnt[NBUCK];
    __shared__ int   start[NBUCK + 1];
    __shared__ int   cursor[NBUCK];
    __shared__ float accbuf[256];

    const int frame = blockIdx.x >> 6;
    const int sub   = blockIdx.x & 63;
    const int tid   = threadIdx.x;

    const float* q = traj + (size_t)frame * (N_ATOMS * 3);
    for (int a = tid; a < N_ATOMS; a += 256) {
        qx[a] = q[3 * a + 0]; qy[a] = q[3 * a + 1]; qz[a] = q[3 * a + 2];
    }
    if (tid < NBUCK) cnt[tid] = 0;
    __syncthreads();

    const float L = cell[0];
    const float invL = 1.0f / L;
    const float cutoff_sq = 0.25f * L * L;
    const float inv_bw = (float)NBUCK / (0.5f * L);

    float dval[8]; int dbuck[8];
    #pragma unroll
    for (int s = 0; s < 8; ++s) {
        const int qidx = s * 256 + tid;
        const int rp   = sub * 4 + (qidx >> 9);
        const int qq   = qidx & 511;
        const bool inA = qq < (511 - rp);
        const int i = inA ? rp : (510 - rp);
        const int j = inA ? (rp + 1 + qq) : qq;
        const bool vp = !(rp == 255 && !inA);
        float dx = qx[j] - qx[i], dy = qy[j] - qy[i], dz = qz[j] - qz[i];
        dx -= L * floorf(dx * invL + 0.5f);
        dy -= L * floorf(dy * invL + 0.5f);
        dz -= L * floorf(dz * invL + 0.5f);
        const float d2 = dx * dx + dy * dy + dz * dz;
        dbuck[s] = -1; dval[s] = 0.0f;
        if (vp && d2 < cutoff_sq && d2 != 0.0f) {
            const float d = sqrtf(d2);
            int bu = (int)(d * inv_bw);
            if (bu > NBUCK - 1) bu = NBUCK - 1;
            dval[s] = d; dbuck[s] = bu;
            atomicAdd(&cnt[bu], 1);
        }
    }
    __syncthreads();
    if (tid < NBUCK) {
        const int v = cnt[tid];
        int incl = v;
        #pragma unroll
        for (int off = 1; off < NBUCK; off <<= 1) {
            const int n = __shfl_up(incl, off, 64);
            if (tid >= off) incl += n;
        }
        start[tid + 1] = incl; cursor[tid] = incl - v;
        if (tid == 0) start[0] = 0;
    }
    __syncthreads();
    #pragma unroll
    for (int s = 0; s < 8; ++s) {
        if (dbuck[s] >= 0) {
            const int pos = atomicAdd(&cursor[dbuck[s]], 1);
            dsorted[pos] = dval[s];
        }
    }
    __syncthreads();

    const int k = tid & 127;
    const int g = tid >> 7;
    float acc = 0.0f;
    if (k < B) {
        const float rk = r_list[k];
        const float c2 = 100.0f * rk, c3 = -50.0f * rk * rk;
        int blo = (int)(fmaxf((rk - WIN) * inv_bw, 0.0f));
        int bhi = (int)((rk + WIN) * inv_bw);
        if (bhi > NBUCK - 1) bhi = NBUCK - 1;
        for (int idx = start[blo] + g; idx < start[bhi + 1]; idx += 2) {
            const float d = dsorted[idx];
            acc += __expf(fmaf(d, fmaf(-50.0f, d, c2), c3));
        }
    }
    accbuf[tid] = acc;
    __syncthreads();
    if (tid < MAX_B)
        atomicAdd(&hist[(blockIdx.x & 15) * MAX_B + tid], accbuf[tid] + accbuf[tid + 128]);
}

__global__ __launch_bounds__(256) void finalize_kernel(
    const float* __restrict__ r_list, const float* __restrict__ cell,
    const float* __restrict__ hist, float* __restrict__ out, int B, int F)
{
    const int k = blockIdx.x * blockDim.x + threadIdx.x;
    if (k >= B) return;
    float h = 0.0f;
    for (int rep = 0; rep < 16; ++rep) h += hist[rep * MAX_B + k];
    const float r = r_list[k];
    out[k] = r;
    const float det = cell[0] * cell[4] * cell[8];
    const float rp = r + 0.05f, rm = r - 0.05f;
    const float v = (4.0f * (float)M_PI / 3.0f) * (rp * rp * rp - rm * rm * rm);
    h = h * 0.3989422804014327f / (float)F;
    out[B + k] = h / v * det / (float)(N_ATOMS - 1) / (float)N_ATOMS * 2.0f;
}

extern "C" void kernel_launch(void* const* d_in, const int* in_sizes, int n_in,
                              void* d_out, int out_size, void* d_ws, size_t ws_size,
                              hipStream_t stream) {
    const float* traj   = (const float*)d_in[0];
    const float* cell   = (const float*)d_in[1];
    const float* r_list = (const float*)d_in[2];
    float* out  = (float*)d_out;
    float* part = (float*)d_ws;

    int B = in_sizes[2];
    int F = in_sizes[0] / (N_ATOMS * 3);
    int nblocks = F * 64;

    if (ws_size >= (size_t)MAX_B * nblocks * sizeof(float)) {
        void* args[] = {&traj, &cell, &r_list, &part, &out, &B, &F, &nblocks};
        hipLaunchCooperativeKernel((const void*)rdf_fused, dim3(nblocks), dim3(256),
                                   args, 0, stream);
    } else {
        hipLaunchKernelGGL(zero_kernel, dim3(8), dim3(256), 0, stream,
                           part, 16 * MAX_B);
        hipLaunchKernelGGL(pair_kernel_atomic, dim3(nblocks), dim3(256), 0, stream,
                           traj, cell, r_list, part, B);
        hipLaunchKernelGGL(finalize_kernel, dim3(1), dim3(MAX_B), 0, stream,
                           r_list, cell, part, out, B, F);
    }
}

// Round 5
// 133.070 us; speedup vs baseline: 1.2475x; 1.2475x over previous
//
#include <hip/hip_runtime.h>
#include <math.h>

#define N_ATOMS 512
#define MAX_B 128
#define NBUCK 32
#define WIN 0.65f   // 6.5 sigma; exp(-50*0.65^2) ~ 7e-10, negligible vs 0.235 budget
#define SUBS 32                       // blocks per frame
#define RPPB 8                        // bow-tie row-pairs per block
#define PAIRS_PB (RPPB * N_ATOMS)     // 4096 pairs per block
#define PPT (PAIRS_PB / 256)          // 16 pairs per thread

// ---------------- single-dispatch kernel (main path) ----------------
// Grid: F*32 blocks, 256 threads, 2 blocks/CU. Each block: 8 bow-tie row-pairs
// = 4096 pairs -> bucket-sorted distances -> windowed bin-centric partial
// histogram -> unique partial slot part[block][bin]. Last block (ticket) does
// the acquire fence, column-reduces all partials, and writes (r_list, gr).
__global__ __launch_bounds__(256, 2) void rdf_onepass(
    const float* __restrict__ traj, const float* __restrict__ cell,
    const float* __restrict__ r_list, float* __restrict__ part,
    unsigned int* __restrict__ counter, float* __restrict__ out,
    int B, int F)
{
    __shared__ float qx[N_ATOMS], qy[N_ATOMS], qz[N_ATOMS];
    __shared__ float dsorted[PAIRS_PB];
    __shared__ int   cnt[NBUCK];
    __shared__ int   start[NBUCK + 1];
    __shared__ int   cursor[NBUCK];
    __shared__ float accbuf[256];
    __shared__ float4 red[8][32];
    __shared__ unsigned int ticket;

    const int frame = blockIdx.x >> 5;          // / SUBS
    const int sub   = blockIdx.x & (SUBS - 1);
    const int tid   = threadIdx.x;

    const float* q = traj + (size_t)frame * (N_ATOMS * 3);
    for (int a = tid; a < N_ATOMS; a += 256) {
        qx[a] = q[3 * a + 0];
        qy[a] = q[3 * a + 1];
        qz[a] = q[3 * a + 2];
    }
    if (tid < NBUCK) cnt[tid] = 0;
    __syncthreads();

    const float L = cell[0];
    const float invL = 1.0f / L;
    const float cutoff_sq = 0.25f * L * L;
    const float inv_bw = (float)NBUCK / (0.5f * L);

    // ---- A1: distances + bucket counts (16 pairs/thread, bow-tie decode) ----
    float dval[PPT];
    #pragma unroll
    for (int s = 0; s < PPT; ++s) {
        const int qidx = s * 256 + tid;                 // [0, 4096)
        const int rp   = sub * RPPB + (qidx >> 9);      // row-pair [0, 256)
        const int qq   = qidx & (N_ATOMS - 1);
        const bool inA = qq < (N_ATOMS - 1 - rp);       // row rp: j in (rp, 511]
        const int i = inA ? rp : (N_ATOMS - 2 - rp);    // partner row 510-rp
        const int j = inA ? (rp + 1 + qq) : qq;
        const bool vp = !((rp == (N_ATOMS / 2 - 1)) && !inA); // middle row: half only

        float dx = qx[j] - qx[i];
        float dy = qy[j] - qy[i];
        float dz = qz[j] - qz[i];
        dx -= L * floorf(dx * invL + 0.5f);
        dy -= L * floorf(dy * invL + 0.5f);
        dz -= L * floorf(dz * invL + 0.5f);
        const float d2 = dx * dx + dy * dy + dz * dz;

        dval[s] = -1.0f;
        if (vp && d2 < cutoff_sq && d2 != 0.0f) {
            const float d = sqrtf(d2);
            dval[s] = d;
            int bu = (int)(d * inv_bw);
            if (bu > NBUCK - 1) bu = NBUCK - 1;
            atomicAdd(&cnt[bu], 1);                     // native ds_add_u32
        }
    }
    __syncthreads();

    // ---- A2: exclusive prefix scan of 32 bucket counts (one wave) ----
    if (tid < NBUCK) {
        const int v = cnt[tid];
        int incl = v;
        #pragma unroll
        for (int off = 1; off < NBUCK; off <<= 1) {
            const int n = __shfl_up(incl, off, 64);
            if (tid >= off) incl += n;
        }
        start[tid + 1] = incl;
        cursor[tid] = incl - v;
        if (tid == 0) start[0] = 0;
    }
    __syncthreads();

    // ---- A3: scatter distances into bucket-sorted order ----
    #pragma unroll
    for (int s = 0; s < PPT; ++s) {
        const float d = dval[s];
        if (d >= 0.0f) {
            int bu = (int)(d * inv_bw);
            if (bu > NBUCK - 1) bu = NBUCK - 1;
            const int pos = atomicAdd(&cursor[bu], 1);
            dsorted[pos] = d;
        }
    }
    __syncthreads();

    // ---- A4: bin-centric accumulation over windowed bucket range ----
    const int k = tid & 127;
    const int g = tid >> 7;
    float acc = 0.0f;
    if (k < B) {
        const float rk = r_list[k];
        const float c2 = 100.0f * rk;
        const float c3 = -50.0f * rk * rk;
        int blo = (int)(fmaxf((rk - WIN) * inv_bw, 0.0f));
        int bhi = (int)((rk + WIN) * inv_bw);
        if (bhi > NBUCK - 1) bhi = NBUCK - 1;
        const int lo = start[blo];
        const int hi = start[bhi + 1];
        for (int idx = lo + g; idx < hi; idx += 2) {
            const float d = dsorted[idx];
            acc += __expf(fmaf(d, fmaf(-50.0f, d, c2), c3));
        }
    }
    accbuf[tid] = acc;
    __syncthreads();

    // unique-slot partial write: part[block][bin] (coalesced 512B)
    if (tid < MAX_B)
        part[(size_t)blockIdx.x * MAX_B + tid] = accbuf[tid] + accbuf[tid + 128];

    // ---- release + ticket ----
    __threadfence();                 // make partial visible device-wide
    __syncthreads();
    if (tid == 0) ticket = atomicAdd(counter, 1u);
    __syncthreads();
    if (ticket != (unsigned)(gridDim.x - 1)) return;

    // ---- last block: acquire + reduce all partials + write outputs ----
    __threadfence();
    const int nblk = gridDim.x;
    const int per_seg = nblk >> 3;          // nblk = F*32, divisible by 8
    const int seg = tid >> 5;               // 8 segments over blocks
    const int t4  = tid & 31;               // 32 float4 = 128 bins
    const float4* p4 = (const float4*)part;
    float4 s4 = make_float4(0.0f, 0.0f, 0.0f, 0.0f);
    const int b_lo = seg * per_seg;
    for (int blk = b_lo; blk < b_lo + per_seg; ++blk) {
        const float4 v = p4[(size_t)blk * 32 + t4];
        s4.x += v.x; s4.y += v.y; s4.z += v.z; s4.w += v.w;
    }
    red[seg][t4] = s4;
    __syncthreads();
    if (tid < 32) {
        float4 h = red[0][tid];
        #pragma unroll
        for (int s = 1; s < 8; ++s) {
            const float4 v = red[s][tid];
            h.x += v.x; h.y += v.y; h.z += v.z; h.w += v.w;
        }
        const float det = cell[0] * cell[4] * cell[8];
        const float hv[4] = {h.x, h.y, h.z, h.w};
        #pragma unroll
        for (int c = 0; c < 4; ++c) {
            const int kk = tid * 4 + c;
            if (kk < B) {
                const float r = r_list[kk];
                out[kk] = r;                               // output 0: r_list
                const float rp_ = r + 0.05f;
                const float rm_ = r - 0.05f;
                const float vsh = (4.0f * (float)M_PI / 3.0f) *
                                  (rp_ * rp_ * rp_ - rm_ * rm_ * rm_);
                const float hh = hv[c] * 0.3989422804014327f / (float)F;
                out[B + kk] = hh / vsh * det /
                              (float)(N_ATOMS - 1) / (float)N_ATOMS * 2.0f;
            }
        }
    }
}

// ---------------- fallback path (tiny ws): 3 dispatches ----------------
__global__ void zero_kernel(float* p, int n) {
    int t = blockIdx.x * blockDim.x + threadIdx.x;
    if (t < n) p[t] = 0.0f;
}

__global__ __launch_bounds__(256) void pair_kernel_atomic(
    const float* __restrict__ traj, const float* __restrict__ cell,
    const float* __restrict__ r_list, float* __restrict__ hist, int B)
{
    __shared__ float qx[N_ATOMS], qy[N_ATOMS], qz[N_ATOMS];
    __shared__ float dsorted[2048];
    __shared__ int cnt[NBUCK];
    __shared__ int start[NBUCK + 1];
    __shared__ int cursor[NBUCK];
    __shared__ float accbuf[256];

    const int frame = blockIdx.x >> 6;
    const int sub   = blockIdx.x & 63;
    const int tid   = threadIdx.x;
    const float* q = traj + (size_t)frame * (N_ATOMS * 3);
    for (int a = tid; a < N_ATOMS; a += 256) {
        qx[a] = q[3*a+0]; qy[a] = q[3*a+1]; qz[a] = q[3*a+2];
    }
    if (tid < NBUCK) cnt[tid] = 0;
    __syncthreads();

    const float L = cell[0];
    const float invL = 1.0f / L;
    const float cutoff_sq = 0.25f * L * L;
    const float inv_bw = (float)NBUCK / (0.5f * L);

    float dval[8];
    #pragma unroll
    for (int s = 0; s < 8; ++s) {
        const int qidx = s * 256 + tid;
        const int rp   = sub * 4 + (qidx >> 9);
        const int qq   = qidx & 511;
        const bool inA = qq < (511 - rp);
        const int i = inA ? rp : (510 - rp);
        const int j = inA ? (rp + 1 + qq) : qq;
        const bool vp = !(rp == 255 && !inA);
        float dx = qx[j]-qx[i], dy = qy[j]-qy[i], dz = qz[j]-qz[i];
        dx -= L * floorf(dx*invL + 0.5f);
        dy -= L * floorf(dy*invL + 0.5f);
        dz -= L * floorf(dz*invL + 0.5f);
        const float d2 = dx*dx + dy*dy + dz*dz;
        dval[s] = -1.0f;
        if (vp && d2 < cutoff_sq && d2 != 0.0f) {
            const float d = sqrtf(d2);
            dval[s] = d;
            int bu = (int)(d * inv_bw);
            if (bu > NBUCK-1) bu = NBUCK-1;
            atomicAdd(&cnt[bu], 1);
        }
    }
    __syncthreads();
    if (tid < NBUCK) {
        const int v = cnt[tid];
        int incl = v;
        #pragma unroll
        for (int off = 1; off < NBUCK; off <<= 1) {
            const int n = __shfl_up(incl, off, 64);
            if (tid >= off) incl += n;
        }
        start[tid + 1] = incl; cursor[tid] = incl - v;
        if (tid == 0) start[0] = 0;
    }
    __syncthreads();
    #pragma unroll
    for (int s = 0; s < 8; ++s) {
        const float d = dval[s];
        if (d >= 0.0f) {
            int bu = (int)(d * inv_bw);
            if (bu > NBUCK-1) bu = NBUCK-1;
            dsorted[atomicAdd(&cursor[bu], 1)] = d;
        }
    }
    __syncthreads();

    const int k = tid & 127;
    const int g = tid >> 7;
    float acc = 0.0f;
    if (k < B) {
        const float rk = r_list[k];
        const float c2 = 100.0f * rk, c3 = -50.0f * rk * rk;
        int blo = (int)(fmaxf((rk - WIN) * inv_bw, 0.0f));
        int bhi = (int)((rk + WIN) * inv_bw);
        if (bhi > NBUCK-1) bhi = NBUCK-1;
        for (int idx = start[blo] + g; idx < start[bhi + 1]; idx += 2) {
            const float d = dsorted[idx];
            acc += __expf(fmaf(d, fmaf(-50.0f, d, c2), c3));
        }
    }
    accbuf[tid] = acc;
    __syncthreads();
    if (tid < MAX_B)
        atomicAdd(&hist[(blockIdx.x & 15) * MAX_B + tid], accbuf[tid] + accbuf[tid + 128]);
}

__global__ __launch_bounds__(256) void finalize_kernel(
    const float* __restrict__ r_list, const float* __restrict__ cell,
    const float* __restrict__ hist, float* __restrict__ out, int B, int F)
{
    const int k = blockIdx.x * blockDim.x + threadIdx.x;
    if (k >= B) return;
    float h = 0.0f;
    for (int rep = 0; rep < 16; ++rep) h += hist[rep * MAX_B + k];
    const float r = r_list[k];
    out[k] = r;
    const float det = cell[0] * cell[4] * cell[8];
    const float rp = r + 0.05f, rm = r - 0.05f;
    const float v = (4.0f * (float)M_PI / 3.0f) * (rp*rp*rp - rm*rm*rm);
    h = h * 0.3989422804014327f / (float)F;
    out[B + k] = h / v * det / (float)(N_ATOMS - 1) / (float)N_ATOMS * 2.0f;
}

extern "C" void kernel_launch(void* const* d_in, const int* in_sizes, int n_in,
                              void* d_out, int out_size, void* d_ws, size_t ws_size,
                              hipStream_t stream) {
    const float* traj   = (const float*)d_in[0];
    const float* cell   = (const float*)d_in[1];
    const float* r_list = (const float*)d_in[2];
    float* out = (float*)d_out;

    int B = in_sizes[2];
    int F = in_sizes[0] / (N_ATOMS * 3);
    int nblk = F * SUBS;
    const size_t part_bytes = (size_t)nblk * MAX_B * sizeof(float);

    if (ws_size >= part_bytes + sizeof(unsigned int)) {
        float* part = (float*)d_ws;
        unsigned int* counter = (unsigned int*)((char*)d_ws + part_bytes);
        hipMemsetAsync(counter, 0, sizeof(unsigned int), stream);  // capturable
        hipLaunchKernelGGL(rdf_onepass, dim3(nblk), dim3(256), 0, stream,
                           traj, cell, r_list, part, counter, out, B, F);
    } else {
        float* hist = (float*)d_ws;
        hipLaunchKernelGGL(zero_kernel, dim3(8), dim3(256), 0, stream,
                           hist, 16 * MAX_B);
        hipLaunchKernelGGL(pair_kernel_atomic, dim3(F * 64), dim3(256), 0, stream,
                           traj, cell, r_list, hist, B);
        hipLaunchKernelGGL(finalize_kernel, dim3(1), dim3(MAX_B), 0, stream,
                           r_list, cell, hist, out, B, F);
    }
}

// Round 6
// 130.495 us; speedup vs baseline: 1.2721x; 1.0197x over previous
//
#include <hip/hip_runtime.h>
#include <math.h>

#define N_ATOMS 512
#define MAX_B 128
#define NBUCK 64
#define WIN 0.45f   // 4.5 sigma; truncation error in gr ~1e-4, budget 0.235
#define NREP 16     // replicated global histograms

// ---------------- single-dispatch kernel (main path) ----------------
// Grid: F*64 = 1024 blocks, 256 threads (R2's proven geometry: 4 blocks/CU).
// Block = (frame, 4 bow-tie row-pairs) = 2048 pairs -> bucket-sorted distances
// -> windowed bin-centric partial histogram -> global atomicAdd into
// hist[blockIdx%16][bin]. Ticket; last block reduces 16x128 and writes outputs.
__global__ __launch_bounds__(256) void rdf_onepass(
    const float* __restrict__ traj, const float* __restrict__ cell,
    const float* __restrict__ r_list, float* __restrict__ hist,
    unsigned int* __restrict__ counter, float* __restrict__ out,
    int B, int F)
{
    __shared__ float qx[N_ATOMS], qy[N_ATOMS], qz[N_ATOMS];
    __shared__ float dsorted[2048];
    __shared__ int   cnt[NBUCK];
    __shared__ int   start[NBUCK + 1];
    __shared__ int   cursor[NBUCK];
    __shared__ float accbuf[256];
    __shared__ unsigned int ticket;

    const int frame = blockIdx.x >> 6;
    const int sub   = blockIdx.x & 63;
    const int tid   = threadIdx.x;

    const float* q = traj + (size_t)frame * (N_ATOMS * 3);
    for (int a = tid; a < N_ATOMS; a += 256) {
        qx[a] = q[3 * a + 0];
        qy[a] = q[3 * a + 1];
        qz[a] = q[3 * a + 2];
    }
    if (tid < NBUCK) cnt[tid] = 0;
    __syncthreads();

    const float L = cell[0];
    const float invL = 1.0f / L;
    const float cutoff_sq = 0.25f * L * L;
    const float inv_bw = (float)NBUCK / (0.5f * L);

    // ---- A1: distances + bucket counts (8 pairs/thread, bow-tie decode) ----
    float dval[8];
    #pragma unroll
    for (int s = 0; s < 8; ++s) {
        const int qidx = s * 256 + tid;            // [0, 2048)
        const int rp   = sub * 4 + (qidx >> 9);    // row-pair [0, 256)
        const int qq   = qidx & 511;
        const bool inA = qq < (511 - rp);          // row rp: j in (rp, 511]
        const int i = inA ? rp : (510 - rp);       // partner row 510-rp
        const int j = inA ? (rp + 1 + qq) : qq;
        const bool vp = !(rp == 255 && !inA);      // self-paired middle row: half

        float dx = qx[j] - qx[i];
        float dy = qy[j] - qy[i];
        float dz = qz[j] - qz[i];
        dx -= L * floorf(dx * invL + 0.5f);
        dy -= L * floorf(dy * invL + 0.5f);
        dz -= L * floorf(dz * invL + 0.5f);
        const float d2 = dx * dx + dy * dy + dz * dz;

        dval[s] = -1.0f;
        if (vp && d2 < cutoff_sq && d2 != 0.0f) {
            const float d = sqrtf(d2);
            dval[s] = d;
            int bu = (int)(d * inv_bw);
            if (bu > NBUCK - 1) bu = NBUCK - 1;
            atomicAdd(&cnt[bu], 1);                // native ds_add_u32
        }
    }
    __syncthreads();

    // ---- A2: exclusive prefix scan of 64 bucket counts (one wave) ----
    if (tid < NBUCK) {
        const int v = cnt[tid];
        int incl = v;
        #pragma unroll
        for (int off = 1; off < NBUCK; off <<= 1) {
            const int n = __shfl_up(incl, off, 64);
            if (tid >= off) incl += n;
        }
        start[tid + 1] = incl;
        cursor[tid] = incl - v;
        if (tid == 0) start[0] = 0;
    }
    __syncthreads();

    // ---- A3: scatter distances into bucket-sorted order ----
    #pragma unroll
    for (int s = 0; s < 8; ++s) {
        const float d = dval[s];
        if (d >= 0.0f) {
            int bu = (int)(d * inv_bw);
            if (bu > NBUCK - 1) bu = NBUCK - 1;
            const int pos = atomicAdd(&cursor[bu], 1);
            dsorted[pos] = d;
        }
    }
    __syncthreads();

    // ---- A4: bin-centric accumulation over windowed bucket range ----
    const int k = tid & 127;
    const int g = tid >> 7;
    float acc = 0.0f;
    if (k < B) {
        const float rk = r_list[k];
        const float c2 = 100.0f * rk;
        const float c3 = -50.0f * rk * rk;
        int blo = (int)(fmaxf((rk - WIN) * inv_bw, 0.0f));
        int bhi = (int)((rk + WIN) * inv_bw);
        if (bhi > NBUCK - 1) bhi = NBUCK - 1;
        const int lo = start[blo];
        const int hi = start[bhi + 1];
        for (int idx = lo + g; idx < hi; idx += 2) {
            const float d = dsorted[idx];
            acc += __expf(fmaf(d, fmaf(-50.0f, d, c2), c3));
        }
    }
    accbuf[tid] = acc;
    __syncthreads();

    // ---- replicated global histogram accumulate (device-scope fp atomics) ----
    if (tid < MAX_B)
        atomicAdd(&hist[(blockIdx.x & (NREP - 1)) * MAX_B + tid],
                  accbuf[tid] + accbuf[tid + 128]);

    // ---- release + ticket ----
    __threadfence();
    __syncthreads();
    if (tid == 0) ticket = atomicAdd(counter, 1u);
    __syncthreads();
    if (ticket != (unsigned)(gridDim.x - 1)) return;

    // ---- last block: tiny reduce (16x128) + outputs ----
    __threadfence();
    if (tid < MAX_B && tid < B) {
        float h = 0.0f;
        #pragma unroll
        for (int rep = 0; rep < NREP; ++rep) h += hist[rep * MAX_B + tid];
        const float r = r_list[tid];
        out[tid] = r;                              // output 0: r_list
        const float det = cell[0] * cell[4] * cell[8];
        const float rp_ = r + 0.05f;
        const float rm_ = r - 0.05f;
        const float vsh = (4.0f * (float)M_PI / 3.0f) *
                          (rp_ * rp_ * rp_ - rm_ * rm_ * rm_);
        const float hh = h * 0.3989422804014327f / (float)F;
        out[B + tid] = hh / vsh * det /
                       (float)(N_ATOMS - 1) / (float)N_ATOMS * 2.0f;   // output 1
    }
}

// ---------------- fallback path (tiny ws): 3 dispatches ----------------
__global__ void zero_kernel(float* p, int n) {
    int t = blockIdx.x * blockDim.x + threadIdx.x;
    if (t < n) p[t] = 0.0f;
}

__global__ __launch_bounds__(256) void pair_kernel_atomic(
    const float* __restrict__ traj, const float* __restrict__ cell,
    const float* __restrict__ r_list, float* __restrict__ hist, int B)
{
    __shared__ float qx[N_ATOMS], qy[N_ATOMS], qz[N_ATOMS];
    __shared__ float dsorted[2048];
    __shared__ int cnt[NBUCK];
    __shared__ int start[NBUCK + 1];
    __shared__ int cursor[NBUCK];
    __shared__ float accbuf[256];

    const int frame = blockIdx.x >> 6;
    const int sub   = blockIdx.x & 63;
    const int tid   = threadIdx.x;
    const float* q = traj + (size_t)frame * (N_ATOMS * 3);
    for (int a = tid; a < N_ATOMS; a += 256) {
        qx[a] = q[3*a+0]; qy[a] = q[3*a+1]; qz[a] = q[3*a+2];
    }
    if (tid < NBUCK) cnt[tid] = 0;
    __syncthreads();

    const float L = cell[0];
    const float invL = 1.0f / L;
    const float cutoff_sq = 0.25f * L * L;
    const float inv_bw = (float)NBUCK / (0.5f * L);

    float dval[8];
    #pragma unroll
    for (int s = 0; s < 8; ++s) {
        const int qidx = s * 256 + tid;
        const int rp   = sub * 4 + (qidx >> 9);
        const int qq   = qidx & 511;
        const bool inA = qq < (511 - rp);
        const int i = inA ? rp : (510 - rp);
        const int j = inA ? (rp + 1 + qq) : qq;
        const bool vp = !(rp == 255 && !inA);
        float dx = qx[j]-qx[i], dy = qy[j]-qy[i], dz = qz[j]-qz[i];
        dx -= L * floorf(dx*invL + 0.5f);
        dy -= L * floorf(dy*invL + 0.5f);
        dz -= L * floorf(dz*invL + 0.5f);
        const float d2 = dx*dx + dy*dy + dz*dz;
        dval[s] = -1.0f;
        if (vp && d2 < cutoff_sq && d2 != 0.0f) {
            const float d = sqrtf(d2);
            dval[s] = d;
            int bu = (int)(d * inv_bw);
            if (bu > NBUCK-1) bu = NBUCK-1;
            atomicAdd(&cnt[bu], 1);
        }
    }
    __syncthreads();
    if (tid < NBUCK) {
        const int v = cnt[tid];
        int incl = v;
        #pragma unroll
        for (int off = 1; off < NBUCK; off <<= 1) {
            const int n = __shfl_up(incl, off, 64);
            if (tid >= off) incl += n;
        }
        start[tid + 1] = incl; cursor[tid] = incl - v;
        if (tid == 0) start[0] = 0;
    }
    __syncthreads();
    #pragma unroll
    for (int s = 0; s < 8; ++s) {
        const float d = dval[s];
        if (d >= 0.0f) {
            int bu = (int)(d * inv_bw);
            if (bu > NBUCK-1) bu = NBUCK-1;
            dsorted[atomicAdd(&cursor[bu], 1)] = d;
        }
    }
    __syncthreads();

    const int k = tid & 127;
    const int g = tid >> 7;
    float acc = 0.0f;
    if (k < B) {
        const float rk = r_list[k];
        const float c2 = 100.0f * rk, c3 = -50.0f * rk * rk;
        int blo = (int)(fmaxf((rk - WIN) * inv_bw, 0.0f));
        int bhi = (int)((rk + WIN) * inv_bw);
        if (bhi > NBUCK-1) bhi = NBUCK-1;
        for (int idx = start[blo] + g; idx < start[bhi + 1]; idx += 2) {
            const float d = dsorted[idx];
            acc += __expf(fmaf(d, fmaf(-50.0f, d, c2), c3));
        }
    }
    accbuf[tid] = acc;
    __syncthreads();
    if (tid < MAX_B)
        atomicAdd(&hist[(blockIdx.x & (NREP-1)) * MAX_B + tid],
                  accbuf[tid] + accbuf[tid + 128]);
}

__global__ __launch_bounds__(256) void finalize_kernel(
    const float* __restrict__ r_list, const float* __restrict__ cell,
    const float* __restrict__ hist, float* __restrict__ out, int B, int F)
{
    const int k = blockIdx.x * blockDim.x + threadIdx.x;
    if (k >= B) return;
    float h = 0.0f;
    for (int rep = 0; rep < NREP; ++rep) h += hist[rep * MAX_B + k];
    const float r = r_list[k];
    out[k] = r;
    const float det = cell[0] * cell[4] * cell[8];
    const float rp = r + 0.05f, rm = r - 0.05f;
    const float v = (4.0f * (float)M_PI / 3.0f) * (rp*rp*rp - rm*rm*rm);
    h = h * 0.3989422804014327f / (float)F;
    out[B + k] = h / v * det / (float)(N_ATOMS - 1) / (float)N_ATOMS * 2.0f;
}

extern "C" void kernel_launch(void* const* d_in, const int* in_sizes, int n_in,
                              void* d_out, int out_size, void* d_ws, size_t ws_size,
                              hipStream_t stream) {
    const float* traj   = (const float*)d_in[0];
    const float* cell   = (const float*)d_in[1];
    const float* r_list = (const float*)d_in[2];
    float* out = (float*)d_out;

    int B = in_sizes[2];
    int F = in_sizes[0] / (N_ATOMS * 3);
    int nblk = F * 64;

    const size_t hist_bytes = (size_t)NREP * MAX_B * sizeof(float);

    if (ws_size >= hist_bytes + sizeof(unsigned int)) {
        float* hist = (float*)d_ws;
        unsigned int* counter = (unsigned int*)((char*)d_ws + hist_bytes);
        // zero hist + counter in one capturable memset node
        hipMemsetAsync(d_ws, 0, hist_bytes + sizeof(unsigned int), stream);
        hipLaunchKernelGGL(rdf_onepass, dim3(nblk), dim3(256), 0, stream,
                           traj, cell, r_list, hist, counter, out, B, F);
    } else {
        float* hist = (float*)d_ws;   // needs NREP*MAX_B floats
        hipLaunchKernelGGL(zero_kernel, dim3(8), dim3(256), 0, stream,
                           hist, NREP * MAX_B);
        hipLaunchKernelGGL(pair_kernel_atomic, dim3(nblk), dim3(256), 0, stream,
                           traj, cell, r_list, hist, B);
        hipLaunchKernelGGL(finalize_kernel, dim3(1), dim3(MAX_B), 0, stream,
                           r_list, cell, hist, out, B, F);
    }
}

// Round 7
// 81.327 us; speedup vs baseline: 2.0412x; 1.6046x over previous
//
#include <hip/hip_runtime.h>
#include <math.h>

#define N_ATOMS 512
#define MAX_B 128
#define NBUCK 64
#define WIN 0.45f   // 4.5 sigma; truncation error in gr ~1e-4, budget 0.235
#define NREP 16     // replicated global histograms

// ---------------- single-dispatch kernel (main path) ----------------
// Grid: F*64 = 1024 blocks, 256 threads. Block = (frame, 4 bow-tie row-pairs)
// = 2048 pairs -> bucket-sorted distances -> windowed bin-centric partial
// histogram. Cross-block communication is ONLY via device-scope atomics
// (native fp32 add at the coherence point) -> no __threadfence / L2 writeback
// needed. Ticket; last block atomically reads 16x128 hist and writes outputs.
__global__ __launch_bounds__(256) void rdf_onepass(
    const float* __restrict__ traj, const float* __restrict__ cell,
    const float* __restrict__ r_list, float* __restrict__ hist,
    unsigned int* __restrict__ counter, float* __restrict__ out,
    int B, int F)
{
    __shared__ float qx[N_ATOMS], qy[N_ATOMS], qz[N_ATOMS];
    __shared__ float dsorted[2048];
    __shared__ int   cnt[NBUCK];
    __shared__ int   start[NBUCK + 1];
    __shared__ int   cursor[NBUCK];
    __shared__ float accbuf[256];
    __shared__ unsigned int ticket;

    const int frame = blockIdx.x >> 6;
    const int sub   = blockIdx.x & 63;
    const int tid   = threadIdx.x;

    const float* q = traj + (size_t)frame * (N_ATOMS * 3);
    for (int a = tid; a < N_ATOMS; a += 256) {
        qx[a] = q[3 * a + 0];
        qy[a] = q[3 * a + 1];
        qz[a] = q[3 * a + 2];
    }
    if (tid < NBUCK) cnt[tid] = 0;
    __syncthreads();

    const float L = cell[0];
    const float invL = 1.0f / L;
    const float cutoff_sq = 0.25f * L * L;
    const float inv_bw = (float)NBUCK / (0.5f * L);

    // ---- A1: distances + bucket counts (8 pairs/thread, bow-tie decode) ----
    float dval[8];
    #pragma unroll
    for (int s = 0; s < 8; ++s) {
        const int qidx = s * 256 + tid;            // [0, 2048)
        const int rp   = sub * 4 + (qidx >> 9);    // row-pair [0, 256)
        const int qq   = qidx & 511;
        const bool inA = qq < (511 - rp);          // row rp: j in (rp, 511]
        const int i = inA ? rp : (510 - rp);       // partner row 510-rp
        const int j = inA ? (rp + 1 + qq) : qq;
        const bool vp = !(rp == 255 && !inA);      // self-paired middle row: half

        float dx = qx[j] - qx[i];
        float dy = qy[j] - qy[i];
        float dz = qz[j] - qz[i];
        dx -= L * floorf(dx * invL + 0.5f);
        dy -= L * floorf(dy * invL + 0.5f);
        dz -= L * floorf(dz * invL + 0.5f);
        const float d2 = dx * dx + dy * dy + dz * dz;

        dval[s] = -1.0f;
        if (vp && d2 < cutoff_sq && d2 != 0.0f) {
            const float d = sqrtf(d2);
            dval[s] = d;
            int bu = (int)(d * inv_bw);
            if (bu > NBUCK - 1) bu = NBUCK - 1;
            atomicAdd(&cnt[bu], 1);                // native ds_add_u32 (LDS int)
        }
    }
    __syncthreads();

    // ---- A2: exclusive prefix scan of 64 bucket counts (one wave) ----
    if (tid < NBUCK) {
        const int v = cnt[tid];
        int incl = v;
        #pragma unroll
        for (int off = 1; off < NBUCK; off <<= 1) {
            const int n = __shfl_up(incl, off, 64);
            if (tid >= off) incl += n;
        }
        start[tid + 1] = incl;
        cursor[tid] = incl - v;
        if (tid == 0) start[0] = 0;
    }
    __syncthreads();

    // ---- A3: scatter distances into bucket-sorted order ----
    #pragma unroll
    for (int s = 0; s < 8; ++s) {
        const float d = dval[s];
        if (d >= 0.0f) {
            int bu = (int)(d * inv_bw);
            if (bu > NBUCK - 1) bu = NBUCK - 1;
            const int pos = atomicAdd(&cursor[bu], 1);
            dsorted[pos] = d;
        }
    }
    __syncthreads();

    // ---- A4: bin-centric accumulation over windowed bucket range ----
    const int k = tid & 127;
    const int g = tid >> 7;
    float acc = 0.0f;
    if (k < B) {
        const float rk = r_list[k];
        const float c2 = 100.0f * rk;
        const float c3 = -50.0f * rk * rk;
        int blo = (int)(fmaxf((rk - WIN) * inv_bw, 0.0f));
        int bhi = (int)((rk + WIN) * inv_bw);
        if (bhi > NBUCK - 1) bhi = NBUCK - 1;
        const int lo = start[blo];
        const int hi = start[bhi + 1];
        for (int idx = lo + g; idx < hi; idx += 2) {
            const float d = dsorted[idx];
            acc += __expf(fmaf(d, fmaf(-50.0f, d, c2), c3));
        }
    }
    accbuf[tid] = acc;
    __syncthreads();

    // ---- replicated hist accumulate: native device-scope fp32 atomic ----
    if (tid < MAX_B)
        unsafeAtomicAdd(&hist[(blockIdx.x & (NREP - 1)) * MAX_B + tid],
                        accbuf[tid] + accbuf[tid + 128]);

    // ---- ticket (no fence: __syncthreads drains all waves' vmcnt; the hist
    //      atomics are then performed at the device coherence point) ----
    __syncthreads();
    if (tid == 0) ticket = atomicAdd(counter, 1u);
    __syncthreads();
    if (ticket != (unsigned)(gridDim.x - 1)) return;

    // ---- last block: atomic-read the 16x128 hist (coherent) + outputs ----
    if (tid < MAX_B && tid < B) {
        float h = 0.0f;
        #pragma unroll
        for (int rep = 0; rep < NREP; ++rep)
            h += unsafeAtomicAdd(&hist[rep * MAX_B + tid], 0.0f);  // atomic read
        const float r = r_list[tid];
        out[tid] = r;                              // output 0: r_list
        const float det = cell[0] * cell[4] * cell[8];
        const float rp_ = r + 0.05f;
        const float rm_ = r - 0.05f;
        const float vsh = (4.0f * (float)M_PI / 3.0f) *
                          (rp_ * rp_ * rp_ - rm_ * rm_ * rm_);
        const float hh = h * 0.3989422804014327f / (float)F;
        out[B + tid] = hh / vsh * det /
                       (float)(N_ATOMS - 1) / (float)N_ATOMS * 2.0f;   // output 1
    }
}

// ---------------- fallback path (tiny ws): 3 dispatches ----------------
__global__ void zero_kernel(float* p, int n) {
    int t = blockIdx.x * blockDim.x + threadIdx.x;
    if (t < n) p[t] = 0.0f;
}

__global__ __launch_bounds__(256) void pair_kernel_atomic(
    const float* __restrict__ traj, const float* __restrict__ cell,
    const float* __restrict__ r_list, float* __restrict__ hist, int B)
{
    __shared__ float qx[N_ATOMS], qy[N_ATOMS], qz[N_ATOMS];
    __shared__ float dsorted[2048];
    __shared__ int cnt[NBUCK];
    __shared__ int start[NBUCK + 1];
    __shared__ int cursor[NBUCK];
    __shared__ float accbuf[256];

    const int frame = blockIdx.x >> 6;
    const int sub   = blockIdx.x & 63;
    const int tid   = threadIdx.x;
    const float* q = traj + (size_t)frame * (N_ATOMS * 3);
    for (int a = tid; a < N_ATOMS; a += 256) {
        qx[a] = q[3*a+0]; qy[a] = q[3*a+1]; qz[a] = q[3*a+2];
    }
    if (tid < NBUCK) cnt[tid] = 0;
    __syncthreads();

    const float L = cell[0];
    const float invL = 1.0f / L;
    const float cutoff_sq = 0.25f * L * L;
    const float inv_bw = (float)NBUCK / (0.5f * L);

    float dval[8];
    #pragma unroll
    for (int s = 0; s < 8; ++s) {
        const int qidx = s * 256 + tid;
        const int rp   = sub * 4 + (qidx >> 9);
        const int qq   = qidx & 511;
        const bool inA = qq < (511 - rp);
        const int i = inA ? rp : (510 - rp);
        const int j = inA ? (rp + 1 + qq) : qq;
        const bool vp = !(rp == 255 && !inA);
        float dx = qx[j]-qx[i], dy = qy[j]-qy[i], dz = qz[j]-qz[i];
        dx -= L * floorf(dx*invL + 0.5f);
        dy -= L * floorf(dy*invL + 0.5f);
        dz -= L * floorf(dz*invL + 0.5f);
        const float d2 = dx*dx + dy*dy + dz*dz;
        dval[s] = -1.0f;
        if (vp && d2 < cutoff_sq && d2 != 0.0f) {
            const float d = sqrtf(d2);
            dval[s] = d;
            int bu = (int)(d * inv_bw);
            if (bu > NBUCK-1) bu = NBUCK-1;
            atomicAdd(&cnt[bu], 1);
        }
    }
    __syncthreads();
    if (tid < NBUCK) {
        const int v = cnt[tid];
        int incl = v;
        #pragma unroll
        for (int off = 1; off < NBUCK; off <<= 1) {
            const int n = __shfl_up(incl, off, 64);
            if (tid >= off) incl += n;
        }
        start[tid + 1] = incl; cursor[tid] = incl - v;
        if (tid == 0) start[0] = 0;
    }
    __syncthreads();
    #pragma unroll
    for (int s = 0; s < 8; ++s) {
        const float d = dval[s];
        if (d >= 0.0f) {
            int bu = (int)(d * inv_bw);
            if (bu > NBUCK-1) bu = NBUCK-1;
            dsorted[atomicAdd(&cursor[bu], 1)] = d;
        }
    }
    __syncthreads();

    const int k = tid & 127;
    const int g = tid >> 7;
    float acc = 0.0f;
    if (k < B) {
        const float rk = r_list[k];
        const float c2 = 100.0f * rk, c3 = -50.0f * rk * rk;
        int blo = (int)(fmaxf((rk - WIN) * inv_bw, 0.0f));
        int bhi = (int)((rk + WIN) * inv_bw);
        if (bhi > NBUCK-1) bhi = NBUCK-1;
        for (int idx = start[blo] + g; idx < start[bhi + 1]; idx += 2) {
            const float d = dsorted[idx];
            acc += __expf(fmaf(d, fmaf(-50.0f, d, c2), c3));
        }
    }
    accbuf[tid] = acc;
    __syncthreads();
    if (tid < MAX_B)
        atomicAdd(&hist[(blockIdx.x & (NREP-1)) * MAX_B + tid],
                  accbuf[tid] + accbuf[tid + 128]);
}

__global__ __launch_bounds__(256) void finalize_kernel(
    const float* __restrict__ r_list, const float* __restrict__ cell,
    const float* __restrict__ hist, float* __restrict__ out, int B, int F)
{
    const int k = blockIdx.x * blockDim.x + threadIdx.x;
    if (k >= B) return;
    float h = 0.0f;
    for (int rep = 0; rep < NREP; ++rep) h += hist[rep * MAX_B + k];
    const float r = r_list[k];
    out[k] = r;
    const float det = cell[0] * cell[4] * cell[8];
    const float rp = r + 0.05f, rm = r - 0.05f;
    const float v = (4.0f * (float)M_PI / 3.0f) * (rp*rp*rp - rm*rm*rm);
    h = h * 0.3989422804014327f / (float)F;
    out[B + k] = h / v * det / (float)(N_ATOMS - 1) / (float)N_ATOMS * 2.0f;
}

extern "C" void kernel_launch(void* const* d_in, const int* in_sizes, int n_in,
                              void* d_out, int out_size, void* d_ws, size_t ws_size,
                              hipStream_t stream) {
    const float* traj   = (const float*)d_in[0];
    const float* cell   = (const float*)d_in[1];
    const float* r_list = (const float*)d_in[2];
    float* out = (float*)d_out;

    int B = in_sizes[2];
    int F = in_sizes[0] / (N_ATOMS * 3);
    int nblk = F * 64;

    const size_t hist_bytes = (size_t)NREP * MAX_B * sizeof(float);

    if (ws_size >= hist_bytes + sizeof(unsigned int)) {
        float* hist = (float*)d_ws;
        unsigned int* counter = (unsigned int*)((char*)d_ws + hist_bytes);
        // zero hist + counter in one capturable memset node
        hipMemsetAsync(d_ws, 0, hist_bytes + sizeof(unsigned int), stream);
        hipLaunchKernelGGL(rdf_onepass, dim3(nblk), dim3(256), 0, stream,
                           traj, cell, r_list, hist, counter, out, B, F);
    } else {
        float* hist = (float*)d_ws;   // needs NREP*MAX_B floats
        hipLaunchKernelGGL(zero_kernel, dim3(8), dim3(256), 0, stream,
                           hist, NREP * MAX_B);
        hipLaunchKernelGGL(pair_kernel_atomic, dim3(nblk), dim3(256), 0, stream,
                           traj, cell, r_list, hist, B);
        hipLaunchKernelGGL(finalize_kernel, dim3(1), dim3(MAX_B), 0, stream,
                           r_list, cell, hist, out, B, F);
    }
}